// Round 1
// baseline (1468.839 us; speedup 1.0000x reference)
//
#include <hip/hip_runtime.h>
#include <math.h>

// ---------------------------------------------------------------------------
// SAGE pipeline:
//   per branch (x0 = x or x_noisy):
//     P,R = x0 @ Wl.T , x0 @ Wr.T          (dual GEMM, shares A operand)
//     x1  = relu(mean_agg(P) + b + R)      (CSR gather + fused epilogue)
//     ... 3 layers; layer-2 output z -> log_softmax -> y
//   mean_agg(x) @ Wl.T == mean_agg(x @ Wl.T)  (linearity) -> aggregate the
//   projection, so layer 2 gathers 47-dim rows instead of 128-dim.
// CSR built once per call: count (int atomics) -> 1-block scan -> fill.
// ---------------------------------------------------------------------------

__device__ __forceinline__ float wave_reduce_sum(float v) {
#pragma unroll
  for (int m = 1; m < 64; m <<= 1) v += __shfl_xor(v, m, 64);
  return v;
}
__device__ __forceinline__ float wave_reduce_max(float v) {
#pragma unroll
  for (int m = 1; m < 64; m <<= 1) v = fmaxf(v, __shfl_xor(v, m, 64));
  return v;
}

// x_noisy = x + sign(x) * (noise / max(||noise||_2, 1e-12)) * 0.1 ; 1 wave/row
__global__ __launch_bounds__(256, 4) void noisy_kernel(
    const float* __restrict__ x, const float* __restrict__ noise,
    float* __restrict__ xn, int n) {
  int node = (blockIdx.x * blockDim.x + threadIdx.x) >> 6;
  int lane = threadIdx.x & 63;
  if (node >= n) return;
  size_t base = (size_t)node * 128 + 2 * lane;
  float2 nz = *(const float2*)&noise[base];
  float ss = wave_reduce_sum(nz.x * nz.x + nz.y * nz.y);
  float scale = 0.1f / fmaxf(sqrtf(ss), 1e-12f);
  float2 xv = *(const float2*)&x[base];
  float s0 = (xv.x > 0.f) ? 1.f : ((xv.x < 0.f) ? -1.f : 0.f);
  float s1 = (xv.y > 0.f) ? 1.f : ((xv.y < 0.f) ? -1.f : 0.f);
  float2 o;
  o.x = xv.x + s0 * nz.x * scale;
  o.y = xv.y + s1 * nz.y * scale;
  *(float2*)&xn[base] = o;
}

__global__ __launch_bounds__(256, 4) void count_kernel(
    const int* __restrict__ dst, int* __restrict__ cnt, int E) {
  int e = blockIdx.x * blockDim.x + threadIdx.x;
  if (e >= E) return;
  atomicAdd(&cnt[dst[e]], 1);
}

// single-block exclusive scan of cnt -> off (and cur copy). n <= 1024*chunk.
__global__ __launch_bounds__(1024) void scan_kernel(
    const int* __restrict__ cnt, int* __restrict__ off, int* __restrict__ cur,
    int n) {
  __shared__ int part[1024];
  int t = threadIdx.x;
  int chunk = (n + 1023) / 1024;
  int start = t * chunk;
  int end = min(start + chunk, n);
  int s = 0;
  for (int i = start; i < end; ++i) s += cnt[i];
  part[t] = s;
  __syncthreads();
  for (int d = 1; d < 1024; d <<= 1) {
    int v = (t >= d) ? part[t - d] : 0;
    __syncthreads();
    part[t] += v;
    __syncthreads();
  }
  int run = (t > 0) ? part[t - 1] : 0;
  for (int i = start; i < end; ++i) {
    off[i] = run;
    cur[i] = run;
    run += cnt[i];
  }
  if (start < n && end == n) off[n] = run;
}

__global__ __launch_bounds__(256, 4) void fill_kernel(
    const int* __restrict__ src, const int* __restrict__ dst,
    int* __restrict__ cur, int* __restrict__ csr, int E) {
  int e = blockIdx.x * blockDim.x + threadIdx.x;
  if (e >= E) return;
  int pos = atomicAdd(&cur[dst[e]], 1);
  csr[pos] = src[e];
}

// Dual GEMM: P = X @ Wl.T, Q = X @ Wr.T.  X:[n,128] Wl/Wr:[DOUT,128].
// BM=128, BK=16, BN=16*NC. 256 threads, 8 rows x NC cols x 2 mats per thread.
template <int NC, int DOUT>
__global__ __launch_bounds__(256, 2) void dual_gemm(
    const float* __restrict__ X, const float* __restrict__ Wl,
    const float* __restrict__ Wr, float* __restrict__ P, float* __restrict__ Q,
    int n) {
  constexpr int BN = 16 * NC;
  constexpr int BM = 128, BK = 16, K = 128;
  __shared__ float xs[BK][BM + 4];   // +4: keeps 16B align, spreads banks
  __shared__ float wls[BK][BN];
  __shared__ float wrs[BK][BN];
  int tid = threadIdx.x;
  int tr = tid & 15;    // rows 8*tr .. 8*tr+7
  int tc = tid >> 4;    // cols NC*tc ..
  int row0 = blockIdx.x * BM;

  float accl[8][NC];
  float accr[8][NC];
#pragma unroll
  for (int r = 0; r < 8; ++r)
#pragma unroll
    for (int c = 0; c < NC; ++c) accl[r][c] = accr[r][c] = 0.f;

  for (int k0 = 0; k0 < K; k0 += BK) {
    // stage X tile (transposed to [k][row])
#pragma unroll
    for (int idx = tid; idx < BM * BK / 4; idx += 256) {
      int r = idx >> 2;
      int kq = idx & 3;
      float4 v = make_float4(0.f, 0.f, 0.f, 0.f);
      int gr = row0 + r;
      if (gr < n) v = *(const float4*)&X[(size_t)gr * K + k0 + 4 * kq];
      xs[4 * kq + 0][r] = v.x;
      xs[4 * kq + 1][r] = v.y;
      xs[4 * kq + 2][r] = v.z;
      xs[4 * kq + 3][r] = v.w;
    }
    // stage W tiles (transposed to [k][col])
    for (int idx = tid; idx < DOUT * 4; idx += 256) {
      int c = idx >> 2;
      int kq = idx & 3;
      float4 a = *(const float4*)&Wl[(size_t)c * K + k0 + 4 * kq];
      float4 b = *(const float4*)&Wr[(size_t)c * K + k0 + 4 * kq];
      wls[4 * kq + 0][c] = a.x; wls[4 * kq + 1][c] = a.y;
      wls[4 * kq + 2][c] = a.z; wls[4 * kq + 3][c] = a.w;
      wrs[4 * kq + 0][c] = b.x; wrs[4 * kq + 1][c] = b.y;
      wrs[4 * kq + 2][c] = b.z; wrs[4 * kq + 3][c] = b.w;
    }
    if (DOUT < BN) {  // zero-fill padded cols
      for (int idx = tid; idx < (BN - DOUT) * BK; idx += 256) {
        int c = DOUT + idx % (BN - DOUT);
        int kk = idx / (BN - DOUT);
        wls[kk][c] = 0.f;
        wrs[kk][c] = 0.f;
      }
    }
    __syncthreads();
#pragma unroll
    for (int kk = 0; kk < BK; ++kk) {
      float4 a0 = *(const float4*)&xs[kk][8 * tr];
      float4 a1 = *(const float4*)&xs[kk][8 * tr + 4];
      float ar[8] = {a0.x, a0.y, a0.z, a0.w, a1.x, a1.y, a1.z, a1.w};
      float bl[NC], br[NC];
#pragma unroll
      for (int c = 0; c < NC; ++c) {
        bl[c] = wls[kk][NC * tc + c];
        br[c] = wrs[kk][NC * tc + c];
      }
#pragma unroll
      for (int r = 0; r < 8; ++r)
#pragma unroll
        for (int c = 0; c < NC; ++c) {
          accl[r][c] = fmaf(ar[r], bl[c], accl[r][c]);
          accr[r][c] = fmaf(ar[r], br[c], accr[r][c]);
        }
    }
    __syncthreads();
  }
#pragma unroll
  for (int r = 0; r < 8; ++r) {
    int gr = row0 + 8 * tr + r;
    if (gr >= n) continue;
#pragma unroll
    for (int c = 0; c < NC; ++c) {
      int gc = NC * tc + c;
      if (gc < DOUT) {
        P[(size_t)gr * DOUT + gc] = accl[r][c];
        Q[(size_t)gr * DOUT + gc] = accr[r][c];
      }
    }
  }
}

// out = [relu]( mean_{j in N(i)} P[j] + bias + R[i] ), D=128, 1 wave/node
template <bool RELU>
__global__ __launch_bounds__(256, 4) void agg_combine128(
    const float* __restrict__ P, const float* __restrict__ R,
    const float* __restrict__ bias, const int* __restrict__ off,
    const int* __restrict__ csr, float* __restrict__ out, int n) {
  int node = (blockIdx.x * blockDim.x + threadIdx.x) >> 6;
  int lane = threadIdx.x & 63;
  if (node >= n) return;
  int b = off[node], e = off[node + 1];
  float ax0 = 0.f, ay0 = 0.f, ax1 = 0.f, ay1 = 0.f;
  int j = b;
  for (; j + 2 <= e; j += 2) {
    int s0 = csr[j];
    int s1 = csr[j + 1];
    float2 v0 = *(const float2*)&P[(size_t)s0 * 128 + 2 * lane];
    float2 v1 = *(const float2*)&P[(size_t)s1 * 128 + 2 * lane];
    ax0 += v0.x; ay0 += v0.y;
    ax1 += v1.x; ay1 += v1.y;
  }
  if (j < e) {
    int s0 = csr[j];
    float2 v0 = *(const float2*)&P[(size_t)s0 * 128 + 2 * lane];
    ax0 += v0.x; ay0 += v0.y;
  }
  float invd = 1.f / (float)max(e - b, 1);
  float2 rv = *(const float2*)&R[(size_t)node * 128 + 2 * lane];
  float2 bb = *(const float2*)&bias[2 * lane];
  float o0 = (ax0 + ax1) * invd + bb.x + rv.x;
  float o1 = (ay0 + ay1) * invd + bb.y + rv.y;
  if (RELU) {
    o0 = fmaxf(o0, 0.f);
    o1 = fmaxf(o1, 0.f);
  }
  *(float2*)&out[(size_t)node * 128 + 2 * lane] = make_float2(o0, o1);
}

// D=47 variant (layer 2, no relu): z = mean_agg(P2) + bias + R2
__global__ __launch_bounds__(256, 4) void agg_combine47(
    const float* __restrict__ P, const float* __restrict__ R,
    const float* __restrict__ bias, const int* __restrict__ off,
    const int* __restrict__ csr, float* __restrict__ out, int n) {
  int node = (blockIdx.x * blockDim.x + threadIdx.x) >> 6;
  int lane = threadIdx.x & 63;
  if (node >= n) return;
  int b = off[node], e = off[node + 1];
  float a0 = 0.f, a1 = 0.f;
  int j = b;
  for (; j + 2 <= e; j += 2) {
    int s0 = csr[j];
    int s1 = csr[j + 1];
    if (lane < 47) {
      a0 += P[(size_t)s0 * 47 + lane];
      a1 += P[(size_t)s1 * 47 + lane];
    }
  }
  if (j < e) {
    int s0 = csr[j];
    if (lane < 47) a0 += P[(size_t)s0 * 47 + lane];
  }
  if (lane >= 47) return;
  float invd = 1.f / (float)max(e - b, 1);
  out[(size_t)node * 47 + lane] =
      (a0 + a1) * invd + bias[lane] + R[(size_t)node * 47 + lane];
}

__global__ __launch_bounds__(256, 4) void log_softmax47(
    const float* __restrict__ z, float* __restrict__ y, int n) {
  int node = (blockIdx.x * blockDim.x + threadIdx.x) >> 6;
  int lane = threadIdx.x & 63;
  if (node >= n) return;
  float v = (lane < 47) ? z[(size_t)node * 47 + lane] : -INFINITY;
  float m = wave_reduce_max(v);
  float s = wave_reduce_sum((lane < 47) ? expf(v - m) : 0.f);
  float ls = logf(s);
  if (lane < 47) y[(size_t)node * 47 + lane] = v - m - ls;
}

extern "C" void kernel_launch(void* const* d_in, const int* in_sizes, int n_in,
                              void* d_out, int out_size, void* d_ws,
                              size_t ws_size, hipStream_t stream) {
  const float* x = (const float*)d_in[0];
  const int* ei = (const int*)d_in[1];
  const float* noise = (const float*)d_in[2];
  const float* Wl0 = (const float*)d_in[3];
  const float* bl0 = (const float*)d_in[4];
  const float* Wr0 = (const float*)d_in[5];
  const float* Wl1 = (const float*)d_in[6];
  const float* bl1 = (const float*)d_in[7];
  const float* Wr1 = (const float*)d_in[8];
  const float* Wl2 = (const float*)d_in[9];
  const float* bl2 = (const float*)d_in[10];
  const float* Wr2 = (const float*)d_in[11];

  const int N = in_sizes[0] / 128;
  const int E = in_sizes[1] / 2;

  float* out = (float*)d_out;
  float* h_p = out;
  float* y_p = h_p + (size_t)N * 128;
  float* z_p = y_p + (size_t)N * 47;
  float* h_n = z_p + (size_t)N * 47;
  float* y_n = h_n + (size_t)N * 128;
  float* z_n = y_n + (size_t)N * 47;

  char* w = (char*)d_ws;
  auto alloc = [&](size_t bytes) {
    void* p = (void*)w;
    w += (bytes + 511) & ~(size_t)511;
    return p;
  };
  float* P = (float*)alloc((size_t)N * 128 * 4);
  float* R = (float*)alloc((size_t)N * 128 * 4);
  float* XN = (float*)alloc((size_t)N * 128 * 4);
  float* X1 = (float*)alloc((size_t)N * 128 * 4);
  int* cnt = (int*)alloc((size_t)N * 4);
  int* off = (int*)alloc((size_t)(N + 1) * 4);
  int* cur = (int*)alloc((size_t)N * 4);
  int* csr = (int*)alloc((size_t)E * 4);

  // CSR build (once; shared by both branches and all layers)
  hipMemsetAsync(cnt, 0, (size_t)N * 4, stream);
  int eb = (E + 255) / 256;
  count_kernel<<<eb, 256, 0, stream>>>(ei + E, cnt, E);
  scan_kernel<<<1, 1024, 0, stream>>>(cnt, off, cur, N);
  fill_kernel<<<eb, 256, 0, stream>>>(ei, ei + E, cur, csr, E);

  int wave_blocks = (N + 3) / 4;  // 1 wave per node, 4 waves per block
  noisy_kernel<<<wave_blocks, 256, 0, stream>>>(x, noise, XN, N);

  int gemm_blocks = (N + 127) / 128;
  for (int br = 0; br < 2; ++br) {
    const float* x0 = br ? XN : x;
    float* hout = br ? h_n : h_p;
    float* zout = br ? z_n : z_p;
    float* yout = br ? y_n : y_p;

    dual_gemm<8, 128><<<gemm_blocks, 256, 0, stream>>>(x0, Wl0, Wr0, P, R, N);
    agg_combine128<true><<<wave_blocks, 256, 0, stream>>>(P, R, bl0, off, csr,
                                                          X1, N);
    dual_gemm<8, 128><<<gemm_blocks, 256, 0, stream>>>(X1, Wl1, Wr1, P, R, N);
    agg_combine128<true><<<wave_blocks, 256, 0, stream>>>(P, R, bl1, off, csr,
                                                          hout, N);
    dual_gemm<3, 47><<<gemm_blocks, 256, 0, stream>>>(hout, Wl2, Wr2, P, R, N);
    agg_combine47<<<wave_blocks, 256, 0, stream>>>(P, R, bl2, off, csr, zout,
                                                   N);
    log_softmax47<<<wave_blocks, 256, 0, stream>>>(zout, yout, N);
  }
}

// Round 2
// 725.640 us; speedup vs baseline: 2.0242x; 2.0242x over previous
//
#include <hip/hip_runtime.h>
#include <math.h>

// ---------------------------------------------------------------------------
// SAGE pipeline, bf16-MFMA edition.
//   Batched over both branches: M = 2N rows (rows 0..N-1 clean, N..2N-1 noisy).
//   Per layer: [P|R] = Xb @ [Wl;Wr].T via mfma_f32_16x16x32_bf16 (fp32 accum),
//   P stored bf16 (halves gather traffic), R stored fp32.
//   agg: out = [relu](mean_{j in N(i)} P[j] + b + R[i])  (CSR gather, 1 wave/node)
//   Layer 2 agg fuses log_softmax (wave holds all 47 cols).
// ---------------------------------------------------------------------------

typedef unsigned int uint;
typedef unsigned short ushort;
typedef short bf16x8 __attribute__((ext_vector_type(8)));
typedef float f32x4 __attribute__((ext_vector_type(4)));

__device__ __forceinline__ ushort f2b(float f) {  // fp32 -> bf16 RNE
  union { float f; uint u; } v; v.f = f;
  uint u = v.u;
  return (ushort)((u + 0x7FFFu + ((u >> 16) & 1u)) >> 16);
}
__device__ __forceinline__ float b2f(ushort h) {
  union { uint u; float f; } v; v.u = ((uint)h) << 16; return v.f;
}
__device__ __forceinline__ float b2f_lo(uint u) {
  union { uint u; float f; } v; v.u = u << 16; return v.f;
}
__device__ __forceinline__ float b2f_hi(uint u) {
  union { uint u; float f; } v; v.u = u & 0xFFFF0000u; return v.f;
}

__device__ __forceinline__ float wave_reduce_sum(float v) {
#pragma unroll
  for (int m = 1; m < 64; m <<= 1) v += __shfl_xor(v, m, 64);
  return v;
}
__device__ __forceinline__ float wave_reduce_max(float v) {
#pragma unroll
  for (int m = 1; m < 64; m <<= 1) v = fmaxf(v, __shfl_xor(v, m, 64));
  return v;
}

// ------------------------------- CSR build --------------------------------
__global__ __launch_bounds__(256) void count_kernel(
    const int* __restrict__ dst, int* __restrict__ cnt, int E) {
  int e = blockIdx.x * blockDim.x + threadIdx.x;
  if (e >= E) return;
  atomicAdd(&cnt[dst[e]], 1);
}

__global__ __launch_bounds__(1024) void scan_kernel(
    const int* __restrict__ cnt, int* __restrict__ off, int* __restrict__ cur,
    int n) {
  __shared__ int part[1024];
  int t = threadIdx.x;
  int chunk = (n + 1023) / 1024;
  int start = t * chunk;
  int end = min(start + chunk, n);
  int s = 0;
  for (int i = start; i < end; ++i) s += cnt[i];
  part[t] = s;
  __syncthreads();
  for (int d = 1; d < 1024; d <<= 1) {
    int v = (t >= d) ? part[t - d] : 0;
    __syncthreads();
    part[t] += v;
    __syncthreads();
  }
  int run = (t > 0) ? part[t - 1] : 0;
  for (int i = start; i < end; ++i) {
    off[i] = run;
    cur[i] = run;
    run += cnt[i];
  }
  if (start < n && end == n) off[n] = run;
}

__global__ __launch_bounds__(256) void fill_kernel(
    const int* __restrict__ src, const int* __restrict__ dst,
    int* __restrict__ cur, int* __restrict__ csr, int E) {
  int e = blockIdx.x * blockDim.x + threadIdx.x;
  if (e >= E) return;
  int pos = atomicAdd(&cur[dst[e]], 1);
  csr[pos] = src[e];
}

// --------------------- input prep: noisy + bf16 convert --------------------
// XB rows 0..N-1 = bf16(x); rows N..2N-1 = bf16(x + sign(x)*unit(noise)*0.1)
__global__ __launch_bounds__(256) void noisy_convert(
    const float* __restrict__ x, const float* __restrict__ noise,
    ushort* __restrict__ XB, int N) {
  int node = (blockIdx.x * blockDim.x + threadIdx.x) >> 6;
  int lane = threadIdx.x & 63;
  if (node >= N) return;
  size_t base = (size_t)node * 128 + 2 * lane;
  float2 nz = *(const float2*)(noise + base);
  float ss = wave_reduce_sum(nz.x * nz.x + nz.y * nz.y);
  float scale = 0.1f / fmaxf(sqrtf(ss), 1e-12f);
  float2 xv = *(const float2*)(x + base);
  float s0 = (xv.x > 0.f) ? 1.f : ((xv.x < 0.f) ? -1.f : 0.f);
  float s1 = (xv.y > 0.f) ? 1.f : ((xv.y < 0.f) ? -1.f : 0.f);
  float n0 = xv.x + s0 * nz.x * scale;
  float n1 = xv.y + s1 * nz.y * scale;
  uint pc = ((uint)f2b(xv.y) << 16) | f2b(xv.x);
  uint pn = ((uint)f2b(n1) << 16) | f2b(n0);
  *(uint*)(XB + base) = pc;
  *(uint*)(XB + (size_t)N * 128 + base) = pn;
}

__global__ __launch_bounds__(256) void conv_kernel(
    const float* __restrict__ s, ushort* __restrict__ d, int n) {
  int i = blockIdx.x * blockDim.x + threadIdx.x;
  if (i < n) d[i] = f2b(s[i]);
}

// ------------------------------- GEMM (bf16) -------------------------------
// A:[M][128] bf16. W:[*][128] bf16 rows = output cols.
// !L2: grid (rb,2): y=0 -> W rows 0..127 (Wl), store bf16 to Pb[M][128]
//                   y=1 -> W rows 128..255 (Wr), store fp32 to Rf[M][128]
// L2:  grid (rb,1): W 94 rows; cols<47 -> Pb[M][47] bf16, 47..93 -> Rf[M][47] f32
// Block: 128 rows x BN cols, 4 waves (2x2), wave = 64 x NT*16; BK=64, 2 k-steps.
template <int NT, bool L2>
__global__ __launch_bounds__(256) void gemm_bf16(
    const ushort* __restrict__ A, const ushort* __restrict__ W,
    ushort* __restrict__ Pb, float* __restrict__ Rf, int M) {
  constexpr int BN = NT * 32;            // 128 (NT=4) or 96 (NT=3)
  constexpr int WROWS = L2 ? 94 : 128;
  __shared__ ushort As[128 * 72];        // row stride 72 bf16 = 144 B (16B-aligned, bank-safe)
  __shared__ ushort Ws[BN * 72];
  int tid = threadIdx.x;
  int lane = tid & 63, wid = tid >> 6;
  int wm = wid & 1, wn = wid >> 1;
  int lrow = lane & 15, quad = lane >> 4;
  int row0 = blockIdx.x * 128;
  const ushort* Wb = W + (size_t)blockIdx.y * (128 * 128);

  f32x4 acc[4][NT];
#pragma unroll
  for (int mt = 0; mt < 4; ++mt)
#pragma unroll
    for (int nt = 0; nt < NT; ++nt) acc[mt][nt] = (f32x4)(0.f);

  for (int k0 = 0; k0 < 128; k0 += 64) {
    // stage A tile: 128 rows x 64 bf16 (16B chunks)
    for (int c = tid; c < 128 * 8; c += 256) {
      int r = c >> 3, kc = c & 7;
      int gr = row0 + r;
      uint4 v = make_uint4(0, 0, 0, 0);
      if (gr < M) v = *(const uint4*)(A + (size_t)gr * 128 + k0 + kc * 8);
      *(uint4*)(As + r * 72 + kc * 8) = v;
    }
    // stage W tile: BN rows x 64 bf16
    for (int c = tid; c < BN * 8; c += 256) {
      int r = c >> 3, kc = c & 7;
      uint4 v = make_uint4(0, 0, 0, 0);
      if (r < WROWS) v = *(const uint4*)(Wb + (size_t)r * 128 + k0 + kc * 8);
      *(uint4*)(Ws + r * 72 + kc * 8) = v;
    }
    __syncthreads();
#pragma unroll
    for (int ks = 0; ks < 64; ks += 32) {
      bf16x8 af[4], bw[NT];
#pragma unroll
      for (int mt = 0; mt < 4; ++mt)
        af[mt] = *(const bf16x8*)(As + (wm * 64 + mt * 16 + lrow) * 72 + ks + quad * 8);
#pragma unroll
      for (int nt = 0; nt < NT; ++nt)
        bw[nt] = *(const bf16x8*)(Ws + (wn * NT * 16 + nt * 16 + lrow) * 72 + ks + quad * 8);
#pragma unroll
      for (int mt = 0; mt < 4; ++mt)
#pragma unroll
        for (int nt = 0; nt < NT; ++nt)
          acc[mt][nt] = __builtin_amdgcn_mfma_f32_16x16x32_bf16(
              af[mt], bw[nt], acc[mt][nt], 0, 0, 0);
    }
    __syncthreads();
  }
  // epilogue: C/D layout col=lane&15, row=quad*4+reg
#pragma unroll
  for (int mt = 0; mt < 4; ++mt) {
#pragma unroll
    for (int nt = 0; nt < NT; ++nt) {
#pragma unroll
      for (int rg = 0; rg < 4; ++rg) {
        int row = row0 + wm * 64 + mt * 16 + quad * 4 + rg;
        if (row >= M) continue;
        int col = wn * NT * 16 + nt * 16 + lrow;
        float v = acc[mt][nt][rg];
        if (!L2) {
          if (blockIdx.y == 0)
            Pb[(size_t)row * 128 + col] = f2b(v);
          else
            Rf[(size_t)row * 128 + col] = v;
        } else {
          if (col < 47)
            Pb[(size_t)row * 47 + col] = f2b(v);
          else if (col < 94)
            Rf[(size_t)row * 47 + (col - 47)] = v;
        }
      }
    }
  }
}

// ------------------------------ aggregation --------------------------------
// 1 wave per (branch,node). out = [relu](mean P[j] + bias + R[i]).
template <bool RELU, bool WF32, bool WB16>
__global__ __launch_bounds__(256) void agg128(
    const ushort* __restrict__ Pb, const float* __restrict__ Rf,
    const float* __restrict__ bias, const int* __restrict__ off,
    const int* __restrict__ csr, float* __restrict__ f0,
    float* __restrict__ f1, ushort* __restrict__ bout, int N) {
  int gw = (blockIdx.x * blockDim.x + threadIdx.x) >> 6;
  int lane = threadIdx.x & 63;
  if (gw >= 2 * N) return;
  int br = (gw >= N) ? 1 : 0;
  int node = gw - br * N;
  int ra = br * N;
  int b = off[node], e = off[node + 1];
  float a0 = 0.f, a1 = 0.f, c0 = 0.f, c1 = 0.f;
  int j = b;
  for (; j + 2 <= e; j += 2) {
    int s0 = csr[j] + ra, s1 = csr[j + 1] + ra;
    uint u0 = *(const uint*)(Pb + (size_t)s0 * 128 + 2 * lane);
    uint u1 = *(const uint*)(Pb + (size_t)s1 * 128 + 2 * lane);
    a0 += b2f_lo(u0); a1 += b2f_hi(u0);
    c0 += b2f_lo(u1); c1 += b2f_hi(u1);
  }
  if (j < e) {
    uint u0 = *(const uint*)(Pb + (size_t)(csr[j] + ra) * 128 + 2 * lane);
    a0 += b2f_lo(u0); a1 += b2f_hi(u0);
  }
  float invd = 1.f / (float)max(e - b, 1);
  float2 rv = *(const float2*)(Rf + (size_t)gw * 128 + 2 * lane);
  float o0 = (a0 + c0) * invd + bias[2 * lane] + rv.x;
  float o1 = (a1 + c1) * invd + bias[2 * lane + 1] + rv.y;
  if (RELU) { o0 = fmaxf(o0, 0.f); o1 = fmaxf(o1, 0.f); }
  if (WF32) {
    float* dst = (br ? f1 : f0) + (size_t)node * 128 + 2 * lane;
    *(float2*)dst = make_float2(o0, o1);
  }
  if (WB16) {
    uint pk = ((uint)f2b(o1) << 16) | f2b(o0);
    *(uint*)(bout + (size_t)gw * 128 + 2 * lane) = pk;
  }
}

// layer 2: z = mean P47[j] + bias + R47[i]; fused log_softmax -> y
__global__ __launch_bounds__(256) void agg47_softmax(
    const ushort* __restrict__ Pb, const float* __restrict__ Rf,
    const float* __restrict__ bias, const int* __restrict__ off,
    const int* __restrict__ csr, float* __restrict__ z0,
    float* __restrict__ z1, float* __restrict__ y0, float* __restrict__ y1,
    int N) {
  int gw = (blockIdx.x * blockDim.x + threadIdx.x) >> 6;
  int lane = threadIdx.x & 63;
  if (gw >= 2 * N) return;
  int br = (gw >= N) ? 1 : 0;
  int node = gw - br * N;
  int ra = br * N;
  int b = off[node], e = off[node + 1];
  bool act = lane < 47;
  float a0 = 0.f, a1 = 0.f;
  int j = b;
  for (; j + 2 <= e; j += 2) {
    int s0 = csr[j] + ra, s1 = csr[j + 1] + ra;
    if (act) {
      a0 += b2f(Pb[(size_t)s0 * 47 + lane]);
      a1 += b2f(Pb[(size_t)s1 * 47 + lane]);
    }
  }
  if (j < e && act) a0 += b2f(Pb[(size_t)(csr[j] + ra) * 47 + lane]);
  float invd = 1.f / (float)max(e - b, 1);
  float z = 0.f;
  if (act) z = (a0 + a1) * invd + bias[lane] + Rf[(size_t)gw * 47 + lane];
  float m = wave_reduce_max(act ? z : -INFINITY);
  float s = wave_reduce_sum(act ? expf(z - m) : 0.f);
  float ls = logf(s);
  if (act) {
    (br ? z1 : z0)[(size_t)node * 47 + lane] = z;
    (br ? y1 : y0)[(size_t)node * 47 + lane] = z - m - ls;
  }
}

// ---------------------------------------------------------------------------
extern "C" void kernel_launch(void* const* d_in, const int* in_sizes, int n_in,
                              void* d_out, int out_size, void* d_ws,
                              size_t ws_size, hipStream_t stream) {
  const float* x = (const float*)d_in[0];
  const int* ei = (const int*)d_in[1];
  const float* noise = (const float*)d_in[2];
  const float* Wl0 = (const float*)d_in[3];
  const float* bl0 = (const float*)d_in[4];
  const float* Wr0 = (const float*)d_in[5];
  const float* Wl1 = (const float*)d_in[6];
  const float* bl1 = (const float*)d_in[7];
  const float* Wr1 = (const float*)d_in[8];
  const float* Wl2 = (const float*)d_in[9];
  const float* bl2 = (const float*)d_in[10];
  const float* Wr2 = (const float*)d_in[11];

  const int N = in_sizes[0] / 128;
  const int E = in_sizes[1] / 2;
  const int M = 2 * N;

  float* out = (float*)d_out;
  float* h_p = out;
  float* y_p = h_p + (size_t)N * 128;
  float* z_p = y_p + (size_t)N * 47;
  float* h_n = z_p + (size_t)N * 47;
  float* y_n = h_n + (size_t)N * 128;
  float* z_n = y_n + (size_t)N * 47;

  char* w = (char*)d_ws;
  auto alloc = [&](size_t bytes) {
    void* p = (void*)w;
    w += (bytes + 511) & ~(size_t)511;
    return p;
  };
  ushort* XB = (ushort*)alloc((size_t)M * 128 * 2);   // activations bf16
  ushort* Pb = (ushort*)alloc((size_t)M * 128 * 2);   // projection bf16
  float* Rf = (float*)alloc((size_t)M * 128 * 4);     // root term fp32
  ushort* WB0 = (ushort*)alloc(256 * 128 * 2);
  ushort* WB1 = (ushort*)alloc(256 * 128 * 2);
  ushort* WB2 = (ushort*)alloc(94 * 128 * 2);
  int* cnt = (int*)alloc((size_t)N * 4);
  int* off = (int*)alloc((size_t)(N + 1) * 4);
  int* cur = (int*)alloc((size_t)N * 4);
  int* csr = (int*)alloc((size_t)E * 4);

  // weights -> bf16, [Wl;Wr] concat
  conv_kernel<<<(128 * 128 + 255) / 256, 256, 0, stream>>>(Wl0, WB0, 128 * 128);
  conv_kernel<<<(128 * 128 + 255) / 256, 256, 0, stream>>>(Wr0, WB0 + 128 * 128, 128 * 128);
  conv_kernel<<<(128 * 128 + 255) / 256, 256, 0, stream>>>(Wl1, WB1, 128 * 128);
  conv_kernel<<<(128 * 128 + 255) / 256, 256, 0, stream>>>(Wr1, WB1 + 128 * 128, 128 * 128);
  conv_kernel<<<(47 * 128 + 255) / 256, 256, 0, stream>>>(Wl2, WB2, 47 * 128);
  conv_kernel<<<(47 * 128 + 255) / 256, 256, 0, stream>>>(Wr2, WB2 + 47 * 128, 47 * 128);

  // CSR build
  hipMemsetAsync(cnt, 0, (size_t)N * 4, stream);
  int eb = (E + 255) / 256;
  count_kernel<<<eb, 256, 0, stream>>>(ei + E, cnt, E);
  scan_kernel<<<1, 1024, 0, stream>>>(cnt, off, cur, N);
  fill_kernel<<<eb, 256, 0, stream>>>(ei, ei + E, cur, csr, E);

  int nwb = (N + 3) / 4;       // 1 wave/node
  int mwb = (M + 3) / 4;       // 1 wave/(branch,node)
  int rb = (M + 127) / 128;    // GEMM row blocks

  noisy_convert<<<nwb, 256, 0, stream>>>(x, noise, XB, N);

  // layer 0
  gemm_bf16<4, false><<<dim3(rb, 2), 256, 0, stream>>>(XB, WB0, Pb, Rf, M);
  agg128<true, false, true><<<mwb, 256, 0, stream>>>(Pb, Rf, bl0, off, csr,
                                                     nullptr, nullptr, XB, N);
  // layer 1 (h outputs + bf16 for next layer)
  gemm_bf16<4, false><<<dim3(rb, 2), 256, 0, stream>>>(XB, WB1, Pb, Rf, M);
  agg128<true, true, true><<<mwb, 256, 0, stream>>>(Pb, Rf, bl1, off, csr, h_p,
                                                    h_n, XB, N);
  // layer 2 + fused log_softmax
  gemm_bf16<3, true><<<dim3(rb, 1), 256, 0, stream>>>(XB, WB2, Pb, Rf, M);
  agg47_softmax<<<mwb, 256, 0, stream>>>(Pb, Rf, bl2, off, csr, z_p, z_n, y_p,
                                         y_n, N);
}

// Round 3
// 616.942 us; speedup vs baseline: 2.3808x; 1.1762x over previous
//
#include <hip/hip_runtime.h>
#include <math.h>

// ---------------------------------------------------------------------------
// SAGE pipeline, bf16-MFMA edition.
//   Batched over both branches: M = 2N rows (rows 0..N-1 clean, N..2N-1 noisy).
//   Per layer: [P|R] = Xb @ [Wl;Wr].T via mfma_f32_16x16x32_bf16 (fp32 accum),
//   P stored bf16 (halves gather traffic), R stored fp32.
//   agg: out = [relu](mean_{j in N(i)} P[j] + b + R[i])  (CSR gather, 1 wave/node)
//   Layer 2 agg fuses log_softmax (wave holds all 47 cols).
//   CSR build: count (atomics) -> 3-pass hierarchical scan -> fill.
//   (Round-2 post-mortem: the old single-block scan was 110 us on one CU.)
// ---------------------------------------------------------------------------

typedef unsigned int uint;
typedef unsigned short ushort;
typedef short bf16x8 __attribute__((ext_vector_type(8)));
typedef float f32x4 __attribute__((ext_vector_type(4)));

__device__ __forceinline__ ushort f2b(float f) {  // fp32 -> bf16 RNE
  union { float f; uint u; } v; v.f = f;
  uint u = v.u;
  return (ushort)((u + 0x7FFFu + ((u >> 16) & 1u)) >> 16);
}
__device__ __forceinline__ float b2f(ushort h) {
  union { uint u; float f; } v; v.u = ((uint)h) << 16; return v.f;
}
__device__ __forceinline__ float b2f_lo(uint u) {
  union { uint u; float f; } v; v.u = u << 16; return v.f;
}
__device__ __forceinline__ float b2f_hi(uint u) {
  union { uint u; float f; } v; v.u = u & 0xFFFF0000u; return v.f;
}

__device__ __forceinline__ float wave_reduce_sum(float v) {
#pragma unroll
  for (int m = 1; m < 64; m <<= 1) v += __shfl_xor(v, m, 64);
  return v;
}
__device__ __forceinline__ float wave_reduce_max(float v) {
#pragma unroll
  for (int m = 1; m < 64; m <<= 1) v = fmaxf(v, __shfl_xor(v, m, 64));
  return v;
}

// ------------------------------- CSR build --------------------------------
__global__ __launch_bounds__(256) void count_kernel(
    const int* __restrict__ dst, int* __restrict__ cnt, int E) {
  int e = blockIdx.x * blockDim.x + threadIdx.x;
  if (e >= E) return;
  atomicAdd(&cnt[dst[e]], 1);
}

// pass 1: per-block (1024 elems) local exclusive scan + block total.
__global__ __launch_bounds__(256) void scan_blocks(
    const int* __restrict__ cnt, int* __restrict__ loc,
    int* __restrict__ bsum, int n) {
  __shared__ int ls[4];
  int t = threadIdx.x;
  int base = blockIdx.x * 1024 + t * 4;
  int v[4];
  int s = 0;
#pragma unroll
  for (int i = 0; i < 4; ++i) {
    v[i] = (base + i < n) ? cnt[base + i] : 0;
    s += v[i];
  }
  int lane = t & 63, wid = t >> 6;
  int ps = s;
#pragma unroll
  for (int d = 1; d < 64; d <<= 1) {
    int o = __shfl_up(ps, d, 64);
    if (lane >= d) ps += o;
  }
  if (lane == 63) ls[wid] = ps;
  __syncthreads();
  if (t == 0) {
    int r = 0;
#pragma unroll
    for (int w = 0; w < 4; ++w) { int x = ls[w]; ls[w] = r; r += x; }
  }
  __syncthreads();
  int run = ps - s + ls[wid];  // exclusive prefix within block
#pragma unroll
  for (int i = 0; i < 4; ++i) {
    if (base + i < n) loc[base + i] = run;
    run += v[i];
  }
  if (t == 255) bsum[blockIdx.x] = ps + ls[wid];  // block total (inclusive)
}

// pass 2: exclusive scan of block sums (nb <= 256), single block.
__global__ __launch_bounds__(256) void scan_bsums(int* __restrict__ bsum,
                                                  int nb) {
  __shared__ int ls[4];
  int t = threadIdx.x;
  int v = (t < nb) ? bsum[t] : 0;
  int lane = t & 63, wid = t >> 6;
  int ps = v;
#pragma unroll
  for (int d = 1; d < 64; d <<= 1) {
    int o = __shfl_up(ps, d, 64);
    if (lane >= d) ps += o;
  }
  if (lane == 63) ls[wid] = ps;
  __syncthreads();
  if (t == 0) {
    int r = 0;
#pragma unroll
    for (int w = 0; w < 4; ++w) { int x = ls[w]; ls[w] = r; r += x; }
  }
  __syncthreads();
  if (t < nb) bsum[t] = ps - v + ls[wid];
}

// pass 3: add block offsets; write off, cur, and off[n]=E.
__global__ __launch_bounds__(256) void scan_apply(
    const int* __restrict__ loc, const int* __restrict__ bsum,
    int* __restrict__ off, int* __restrict__ cur, int n, int E) {
  int i = blockIdx.x * 256 + threadIdx.x;
  if (i < n) {
    int v = loc[i] + bsum[i >> 10];
    off[i] = v;
    cur[i] = v;
  }
  if (i == 0) off[n] = E;
}

__global__ __launch_bounds__(256) void fill_kernel(
    const int* __restrict__ src, const int* __restrict__ dst,
    int* __restrict__ cur, int* __restrict__ csr, int E) {
  int e = blockIdx.x * blockDim.x + threadIdx.x;
  if (e >= E) return;
  int pos = atomicAdd(&cur[dst[e]], 1);
  csr[pos] = src[e];
}

// --------------------- input prep: noisy + bf16 convert --------------------
// XB rows 0..N-1 = bf16(x); rows N..2N-1 = bf16(x + sign(x)*unit(noise)*0.1)
__global__ __launch_bounds__(256) void noisy_convert(
    const float* __restrict__ x, const float* __restrict__ noise,
    ushort* __restrict__ XB, int N) {
  int node = (blockIdx.x * blockDim.x + threadIdx.x) >> 6;
  int lane = threadIdx.x & 63;
  if (node >= N) return;
  size_t base = (size_t)node * 128 + 2 * lane;
  float2 nz = *(const float2*)(noise + base);
  float ss = wave_reduce_sum(nz.x * nz.x + nz.y * nz.y);
  float scale = 0.1f / fmaxf(sqrtf(ss), 1e-12f);
  float2 xv = *(const float2*)(x + base);
  float s0 = (xv.x > 0.f) ? 1.f : ((xv.x < 0.f) ? -1.f : 0.f);
  float s1 = (xv.y > 0.f) ? 1.f : ((xv.y < 0.f) ? -1.f : 0.f);
  float n0 = xv.x + s0 * nz.x * scale;
  float n1 = xv.y + s1 * nz.y * scale;
  uint pc = ((uint)f2b(xv.y) << 16) | f2b(xv.x);
  uint pn = ((uint)f2b(n1) << 16) | f2b(n0);
  *(uint*)(XB + base) = pc;
  *(uint*)(XB + (size_t)N * 128 + base) = pn;
}

// all 6 weight matrices -> bf16 in one dispatch (cuts 5 launches)
__global__ __launch_bounds__(256) void conv_weights(
    const float* __restrict__ Wl0, const float* __restrict__ Wr0,
    const float* __restrict__ Wl1, const float* __restrict__ Wr1,
    const float* __restrict__ Wl2, const float* __restrict__ Wr2,
    ushort* __restrict__ WB0, ushort* __restrict__ WB1,
    ushort* __restrict__ WB2) {
  int i = blockIdx.x * 256 + threadIdx.x;
  if (i < 16384) {
    WB0[i] = f2b(Wl0[i]);
    WB0[16384 + i] = f2b(Wr0[i]);
    WB1[i] = f2b(Wl1[i]);
    WB1[16384 + i] = f2b(Wr1[i]);
  }
  if (i < 6016) {
    WB2[i] = f2b(Wl2[i]);
    WB2[6016 + i] = f2b(Wr2[i]);
  }
}

// ------------------------------- GEMM (bf16) -------------------------------
// A:[M][128] bf16. W:[*][128] bf16 rows = output cols.
// !L2: grid (rb,2): y=0 -> W rows 0..127 (Wl), store bf16 to Pb[M][128]
//                   y=1 -> W rows 128..255 (Wr), store fp32 to Rf[M][128]
// L2:  grid (rb,1): W 94 rows; cols<47 -> Pb[M][47] bf16, 47..93 -> Rf[M][47] f32
// Block: 128 rows x BN cols, 4 waves (2x2), wave = 64 x NT*16; BK=64, 2 k-steps.
template <int NT, bool L2>
__global__ __launch_bounds__(256) void gemm_bf16(
    const ushort* __restrict__ A, const ushort* __restrict__ W,
    ushort* __restrict__ Pb, float* __restrict__ Rf, int M) {
  constexpr int BN = NT * 32;            // 128 (NT=4) or 96 (NT=3)
  constexpr int WROWS = L2 ? 94 : 128;
  __shared__ ushort As[128 * 72];        // row stride 72 bf16 = 144 B
  __shared__ ushort Ws[BN * 72];
  int tid = threadIdx.x;
  int lane = tid & 63, wid = tid >> 6;
  int wm = wid & 1, wn = wid >> 1;
  int lrow = lane & 15, quad = lane >> 4;
  int row0 = blockIdx.x * 128;
  const ushort* Wb = W + (size_t)blockIdx.y * (128 * 128);

  f32x4 acc[4][NT];
#pragma unroll
  for (int mt = 0; mt < 4; ++mt)
#pragma unroll
    for (int nt = 0; nt < NT; ++nt) acc[mt][nt] = (f32x4)(0.f);

  for (int k0 = 0; k0 < 128; k0 += 64) {
    for (int c = tid; c < 128 * 8; c += 256) {
      int r = c >> 3, kc = c & 7;
      int gr = row0 + r;
      uint4 v = make_uint4(0, 0, 0, 0);
      if (gr < M) v = *(const uint4*)(A + (size_t)gr * 128 + k0 + kc * 8);
      *(uint4*)(As + r * 72 + kc * 8) = v;
    }
    for (int c = tid; c < BN * 8; c += 256) {
      int r = c >> 3, kc = c & 7;
      uint4 v = make_uint4(0, 0, 0, 0);
      if (r < WROWS) v = *(const uint4*)(Wb + (size_t)r * 128 + k0 + kc * 8);
      *(uint4*)(Ws + r * 72 + kc * 8) = v;
    }
    __syncthreads();
#pragma unroll
    for (int ks = 0; ks < 64; ks += 32) {
      bf16x8 af[4], bw[NT];
#pragma unroll
      for (int mt = 0; mt < 4; ++mt)
        af[mt] = *(const bf16x8*)(As + (wm * 64 + mt * 16 + lrow) * 72 + ks + quad * 8);
#pragma unroll
      for (int nt = 0; nt < NT; ++nt)
        bw[nt] = *(const bf16x8*)(Ws + (wn * NT * 16 + nt * 16 + lrow) * 72 + ks + quad * 8);
#pragma unroll
      for (int mt = 0; mt < 4; ++mt)
#pragma unroll
        for (int nt = 0; nt < NT; ++nt)
          acc[mt][nt] = __builtin_amdgcn_mfma_f32_16x16x32_bf16(
              af[mt], bw[nt], acc[mt][nt], 0, 0, 0);
    }
    __syncthreads();
  }
  // epilogue: C/D layout col=lane&15, row=quad*4+reg
#pragma unroll
  for (int mt = 0; mt < 4; ++mt) {
#pragma unroll
    for (int nt = 0; nt < NT; ++nt) {
#pragma unroll
      for (int rg = 0; rg < 4; ++rg) {
        int row = row0 + wm * 64 + mt * 16 + quad * 4 + rg;
        if (row >= M) continue;
        int col = wn * NT * 16 + nt * 16 + lrow;
        float v = acc[mt][nt][rg];
        if (!L2) {
          if (blockIdx.y == 0)
            Pb[(size_t)row * 128 + col] = f2b(v);
          else
            Rf[(size_t)row * 128 + col] = v;
        } else {
          if (col < 47)
            Pb[(size_t)row * 47 + col] = f2b(v);
          else if (col < 94)
            Rf[(size_t)row * 47 + (col - 47)] = v;
        }
      }
    }
  }
}

// ------------------------------ aggregation --------------------------------
// 1 wave per (branch,node). out = [relu](mean P[j] + bias + R[i]).
template <bool RELU, bool WF32, bool WB16>
__global__ __launch_bounds__(256) void agg128(
    const ushort* __restrict__ Pb, const float* __restrict__ Rf,
    const float* __restrict__ bias, const int* __restrict__ off,
    const int* __restrict__ csr, float* __restrict__ f0,
    float* __restrict__ f1, ushort* __restrict__ bout, int N) {
  int gw = (blockIdx.x * blockDim.x + threadIdx.x) >> 6;
  int lane = threadIdx.x & 63;
  if (gw >= 2 * N) return;
  int br = (gw >= N) ? 1 : 0;
  int node = gw - br * N;
  int ra = br * N;
  int b = off[node], e = off[node + 1];
  float a0 = 0.f, a1 = 0.f, c0 = 0.f, c1 = 0.f;
  int j = b;
  for (; j + 2 <= e; j += 2) {
    int s0 = csr[j] + ra, s1 = csr[j + 1] + ra;
    uint u0 = *(const uint*)(Pb + (size_t)s0 * 128 + 2 * lane);
    uint u1 = *(const uint*)(Pb + (size_t)s1 * 128 + 2 * lane);
    a0 += b2f_lo(u0); a1 += b2f_hi(u0);
    c0 += b2f_lo(u1); c1 += b2f_hi(u1);
  }
  if (j < e) {
    uint u0 = *(const uint*)(Pb + (size_t)(csr[j] + ra) * 128 + 2 * lane);
    a0 += b2f_lo(u0); a1 += b2f_hi(u0);
  }
  float invd = 1.f / (float)max(e - b, 1);
  float2 rv = *(const float2*)(Rf + (size_t)gw * 128 + 2 * lane);
  float o0 = (a0 + c0) * invd + bias[2 * lane] + rv.x;
  float o1 = (a1 + c1) * invd + bias[2 * lane + 1] + rv.y;
  if (RELU) { o0 = fmaxf(o0, 0.f); o1 = fmaxf(o1, 0.f); }
  if (WF32) {
    float* dst = (br ? f1 : f0) + (size_t)node * 128 + 2 * lane;
    *(float2*)dst = make_float2(o0, o1);
  }
  if (WB16) {
    uint pk = ((uint)f2b(o1) << 16) | f2b(o0);
    *(uint*)(bout + (size_t)gw * 128 + 2 * lane) = pk;
  }
}

// layer 2: z = mean P47[j] + bias + R47[i]; fused log_softmax -> y
__global__ __launch_bounds__(256) void agg47_softmax(
    const ushort* __restrict__ Pb, const float* __restrict__ Rf,
    const float* __restrict__ bias, const int* __restrict__ off,
    const int* __restrict__ csr, float* __restrict__ z0,
    float* __restrict__ z1, float* __restrict__ y0, float* __restrict__ y1,
    int N) {
  int gw = (blockIdx.x * blockDim.x + threadIdx.x) >> 6;
  int lane = threadIdx.x & 63;
  if (gw >= 2 * N) return;
  int br = (gw >= N) ? 1 : 0;
  int node = gw - br * N;
  int ra = br * N;
  int b = off[node], e = off[node + 1];
  bool act = lane < 47;
  float a0 = 0.f, a1 = 0.f;
  int j = b;
  for (; j + 2 <= e; j += 2) {
    int s0 = csr[j] + ra, s1 = csr[j + 1] + ra;
    if (act) {
      a0 += b2f(Pb[(size_t)s0 * 47 + lane]);
      a1 += b2f(Pb[(size_t)s1 * 47 + lane]);
    }
  }
  if (j < e && act) a0 += b2f(Pb[(size_t)(csr[j] + ra) * 47 + lane]);
  float invd = 1.f / (float)max(e - b, 1);
  float z = 0.f;
  if (act) z = (a0 + a1) * invd + bias[lane] + Rf[(size_t)gw * 47 + lane];
  float m = wave_reduce_max(act ? z : -INFINITY);
  float s = wave_reduce_sum(act ? expf(z - m) : 0.f);
  float ls = logf(s);
  if (act) {
    (br ? z1 : z0)[(size_t)node * 47 + lane] = z;
    (br ? y1 : y0)[(size_t)node * 47 + lane] = z - m - ls;
  }
}

// ---------------------------------------------------------------------------
extern "C" void kernel_launch(void* const* d_in, const int* in_sizes, int n_in,
                              void* d_out, int out_size, void* d_ws,
                              size_t ws_size, hipStream_t stream) {
  const float* x = (const float*)d_in[0];
  const int* ei = (const int*)d_in[1];
  const float* noise = (const float*)d_in[2];
  const float* Wl0 = (const float*)d_in[3];
  const float* bl0 = (const float*)d_in[4];
  const float* Wr0 = (const float*)d_in[5];
  const float* Wl1 = (const float*)d_in[6];
  const float* bl1 = (const float*)d_in[7];
  const float* Wr1 = (const float*)d_in[8];
  const float* Wl2 = (const float*)d_in[9];
  const float* bl2 = (const float*)d_in[10];
  const float* Wr2 = (const float*)d_in[11];

  const int N = in_sizes[0] / 128;
  const int E = in_sizes[1] / 2;
  const int M = 2 * N;

  float* out = (float*)d_out;
  float* h_p = out;
  float* y_p = h_p + (size_t)N * 128;
  float* z_p = y_p + (size_t)N * 47;
  float* h_n = z_p + (size_t)N * 47;
  float* y_n = h_n + (size_t)N * 128;
  float* z_n = y_n + (size_t)N * 47;

  char* w = (char*)d_ws;
  auto alloc = [&](size_t bytes) {
    void* p = (void*)w;
    w += (bytes + 511) & ~(size_t)511;
    return p;
  };
  ushort* XB = (ushort*)alloc((size_t)M * 128 * 2);   // activations bf16
  ushort* Pb = (ushort*)alloc((size_t)M * 128 * 2);   // projection bf16
  float* Rf = (float*)alloc((size_t)M * 128 * 4);     // root term fp32
  ushort* WB0 = (ushort*)alloc(256 * 128 * 2);
  ushort* WB1 = (ushort*)alloc(256 * 128 * 2);
  ushort* WB2 = (ushort*)alloc(94 * 128 * 2);
  int* cnt = (int*)alloc((size_t)N * 4);
  int* off = (int*)alloc((size_t)(N + 1) * 4);
  int* cur = (int*)alloc((size_t)N * 4);
  int* loc = (int*)alloc((size_t)N * 4);
  int* bsum = (int*)alloc((size_t)256 * 4);
  int* csr = (int*)alloc((size_t)E * 4);

  conv_weights<<<(16384 + 255) / 256, 256, 0, stream>>>(
      Wl0, Wr0, Wl1, Wr1, Wl2, Wr2, WB0, WB1, WB2);

  // CSR build
  hipMemsetAsync(cnt, 0, (size_t)N * 4, stream);
  int eb = (E + 255) / 256;
  count_kernel<<<eb, 256, 0, stream>>>(ei + E, cnt, E);
  int sb = (N + 1023) / 1024;  // scan blocks (<=256 supported)
  scan_blocks<<<sb, 256, 0, stream>>>(cnt, loc, bsum, N);
  scan_bsums<<<1, 256, 0, stream>>>(bsum, sb);
  scan_apply<<<(N + 255) / 256, 256, 0, stream>>>(loc, bsum, off, cur, N, E);
  fill_kernel<<<eb, 256, 0, stream>>>(ei, ei + E, cur, csr, E);

  int nwb = (N + 3) / 4;       // 1 wave/node
  int mwb = (M + 3) / 4;       // 1 wave/(branch,node)
  int rb = (M + 127) / 128;    // GEMM row blocks

  noisy_convert<<<nwb, 256, 0, stream>>>(x, noise, XB, N);

  // layer 0
  gemm_bf16<4, false><<<dim3(rb, 2), 256, 0, stream>>>(XB, WB0, Pb, Rf, M);
  agg128<true, false, true><<<mwb, 256, 0, stream>>>(Pb, Rf, bl0, off, csr,
                                                     nullptr, nullptr, XB, N);
  // layer 1 (h outputs + bf16 for next layer)
  gemm_bf16<4, false><<<dim3(rb, 2), 256, 0, stream>>>(XB, WB1, Pb, Rf, M);
  agg128<true, true, true><<<mwb, 256, 0, stream>>>(Pb, Rf, bl1, off, csr, h_p,
                                                    h_n, XB, N);
  // layer 2 + fused log_softmax
  gemm_bf16<3, true><<<dim3(rb, 1), 256, 0, stream>>>(XB, WB2, Pb, Rf, M);
  agg47_softmax<<<mwb, 256, 0, stream>>>(Pb, Rf, bl2, off, csr, z_p, z_n, y_p,
                                         y_n, N);
}

// Round 4
// 497.934 us; speedup vs baseline: 2.9499x; 1.2390x over previous
//
#include <hip/hip_runtime.h>
#include <math.h>

// ---------------------------------------------------------------------------
// SAGE pipeline, bf16-MFMA, dual-branch-interleaved gather edition.
//   M = 2N rows (0..N-1 clean, N..2N-1 noisy) batched through each GEMM.
//   GEMM epilogues write BRANCH-INTERLEAVED layouts:
//     P2[node][2][128] bf16, R2[node][2][128] f32   (layers 0/1)
//     Pz[node][2][64] bf16, Rz[node][2][64] f32     (layer 2, 47 padded to 64)
//   so one wave per NODE aggregates BOTH branches with ONE gather request per
//   edge (512 B / 256 B payloads). Round-3 evidence: agg kernels were
//   request-latency-bound (agg128 269MB and agg47 127MB both 101.6 us).
// ---------------------------------------------------------------------------

typedef unsigned int uint;
typedef unsigned short ushort;
typedef short bf16x8 __attribute__((ext_vector_type(8)));
typedef float f32x4 __attribute__((ext_vector_type(4)));

__device__ __forceinline__ ushort f2b(float f) {  // fp32 -> bf16 RNE
  union { float f; uint u; } v; v.f = f;
  uint u = v.u;
  return (ushort)((u + 0x7FFFu + ((u >> 16) & 1u)) >> 16);
}
__device__ __forceinline__ float b2f_lo(uint u) {
  union { uint u; float f; } v; v.u = u << 16; return v.f;
}
__device__ __forceinline__ float b2f_hi(uint u) {
  union { uint u; float f; } v; v.u = u & 0xFFFF0000u; return v.f;
}

__device__ __forceinline__ float wave_reduce_sum(float v) {
#pragma unroll
  for (int m = 1; m < 64; m <<= 1) v += __shfl_xor(v, m, 64);
  return v;
}

// ------------------------------- CSR build --------------------------------
__global__ __launch_bounds__(256) void count_kernel(
    const int* __restrict__ dst, int* __restrict__ cnt, int E) {
  int e = blockIdx.x * blockDim.x + threadIdx.x;
  if (e >= E) return;
  atomicAdd(&cnt[dst[e]], 1);
}

// pass 1: per-block (1024 elems) local exclusive scan + block total.
__global__ __launch_bounds__(256) void scan_blocks(
    const int* __restrict__ cnt, int* __restrict__ loc,
    int* __restrict__ bsum, int n) {
  __shared__ int ls[4];
  int t = threadIdx.x;
  int base = blockIdx.x * 1024 + t * 4;
  int v[4];
  int s = 0;
#pragma unroll
  for (int i = 0; i < 4; ++i) {
    v[i] = (base + i < n) ? cnt[base + i] : 0;
    s += v[i];
  }
  int lane = t & 63, wid = t >> 6;
  int ps = s;
#pragma unroll
  for (int d = 1; d < 64; d <<= 1) {
    int o = __shfl_up(ps, d, 64);
    if (lane >= d) ps += o;
  }
  if (lane == 63) ls[wid] = ps;
  __syncthreads();
  if (t == 0) {
    int r = 0;
#pragma unroll
    for (int w = 0; w < 4; ++w) { int x = ls[w]; ls[w] = r; r += x; }
  }
  __syncthreads();
  int run = ps - s + ls[wid];
#pragma unroll
  for (int i = 0; i < 4; ++i) {
    if (base + i < n) loc[base + i] = run;
    run += v[i];
  }
  if (t == 255) bsum[blockIdx.x] = ps + ls[wid];
}

// pass 2: exclusive scan of block sums (nb <= 256), single block.
__global__ __launch_bounds__(256) void scan_bsums(int* __restrict__ bsum,
                                                  int nb) {
  __shared__ int ls[4];
  int t = threadIdx.x;
  int v = (t < nb) ? bsum[t] : 0;
  int lane = t & 63, wid = t >> 6;
  int ps = v;
#pragma unroll
  for (int d = 1; d < 64; d <<= 1) {
    int o = __shfl_up(ps, d, 64);
    if (lane >= d) ps += o;
  }
  if (lane == 63) ls[wid] = ps;
  __syncthreads();
  if (t == 0) {
    int r = 0;
#pragma unroll
    for (int w = 0; w < 4; ++w) { int x = ls[w]; ls[w] = r; r += x; }
  }
  __syncthreads();
  if (t < nb) bsum[t] = ps - v + ls[wid];
}

// pass 3: add block offsets; write off, cur, off[n]=E.
__global__ __launch_bounds__(256) void scan_apply(
    const int* __restrict__ loc, const int* __restrict__ bsum,
    int* __restrict__ off, int* __restrict__ cur, int n, int E) {
  int i = blockIdx.x * 256 + threadIdx.x;
  if (i < n) {
    int v = loc[i] + bsum[i >> 10];
    off[i] = v;
    cur[i] = v;
  }
  if (i == 0) off[n] = E;
}

__global__ __launch_bounds__(256) void fill_kernel(
    const int* __restrict__ src, const int* __restrict__ dst,
    int* __restrict__ cur, int* __restrict__ csr, int E) {
  int e = blockIdx.x * blockDim.x + threadIdx.x;
  if (e >= E) return;
  int pos = atomicAdd(&cur[dst[e]], 1);
  csr[pos] = src[e];
}

// --------------------- input prep: noisy + bf16 convert --------------------
__global__ __launch_bounds__(256) void noisy_convert(
    const float* __restrict__ x, const float* __restrict__ noise,
    ushort* __restrict__ XB, int N) {
  int node = (blockIdx.x * blockDim.x + threadIdx.x) >> 6;
  int lane = threadIdx.x & 63;
  if (node >= N) return;
  size_t base = (size_t)node * 128 + 2 * lane;
  float2 nz = *(const float2*)(noise + base);
  float ss = nz.x * nz.x + nz.y * nz.y;
#pragma unroll
  for (int m = 1; m < 64; m <<= 1) ss += __shfl_xor(ss, m, 64);
  float scale = 0.1f / fmaxf(sqrtf(ss), 1e-12f);
  float2 xv = *(const float2*)(x + base);
  float s0 = (xv.x > 0.f) ? 1.f : ((xv.x < 0.f) ? -1.f : 0.f);
  float s1 = (xv.y > 0.f) ? 1.f : ((xv.y < 0.f) ? -1.f : 0.f);
  float n0 = xv.x + s0 * nz.x * scale;
  float n1 = xv.y + s1 * nz.y * scale;
  uint pc = ((uint)f2b(xv.y) << 16) | f2b(xv.x);
  uint pn = ((uint)f2b(n1) << 16) | f2b(n0);
  *(uint*)(XB + base) = pc;
  *(uint*)(XB + (size_t)N * 128 + base) = pn;
}

__global__ __launch_bounds__(256) void conv_weights(
    const float* __restrict__ Wl0, const float* __restrict__ Wr0,
    const float* __restrict__ Wl1, const float* __restrict__ Wr1,
    const float* __restrict__ Wl2, const float* __restrict__ Wr2,
    ushort* __restrict__ WB0, ushort* __restrict__ WB1,
    ushort* __restrict__ WB2) {
  int i = blockIdx.x * 256 + threadIdx.x;
  if (i < 16384) {
    WB0[i] = f2b(Wl0[i]);
    WB0[16384 + i] = f2b(Wr0[i]);
    WB1[i] = f2b(Wl1[i]);
    WB1[16384 + i] = f2b(Wr1[i]);
  }
  if (i < 6016) {
    WB2[i] = f2b(Wl2[i]);
    WB2[6016 + i] = f2b(Wr2[i]);
  }
}

// ------------------------------- GEMM (bf16) -------------------------------
// A:[M][128] bf16 (row = branch*N+node). W rows = output cols.
// !L2 grid (rb,2): y=0 -> Wl -> P2[node][2][128] bf16
//                  y=1 -> Wr -> R2[node][2][128] f32
// L2  grid (rb,1): 94 W rows; col<47 -> Pz[node][2][64] bf16 (pad cols unwritten)
//                  col in [47,94) -> Rz[node][2][64] f32
template <int NT, bool L2>
__global__ __launch_bounds__(256) void gemm_bf16(
    const ushort* __restrict__ A, const ushort* __restrict__ W,
    ushort* __restrict__ Pb, float* __restrict__ Rf, int M) {
  constexpr int BN = NT * 32;
  constexpr int WROWS = L2 ? 94 : 128;
  __shared__ ushort As[128 * 72];   // row stride 72 bf16 = 144 B (bank-safe)
  __shared__ ushort Ws[BN * 72];
  int tid = threadIdx.x;
  int lane = tid & 63, wid = tid >> 6;
  int wm = wid & 1, wn = wid >> 1;
  int lrow = lane & 15, quad = lane >> 4;
  int row0 = blockIdx.x * 128;
  int N0 = M >> 1;
  const ushort* Wb = W + (size_t)blockIdx.y * (128 * 128);

  f32x4 acc[4][NT];
#pragma unroll
  for (int mt = 0; mt < 4; ++mt)
#pragma unroll
    for (int nt = 0; nt < NT; ++nt) acc[mt][nt] = (f32x4)(0.f);

  for (int k0 = 0; k0 < 128; k0 += 64) {
    for (int c = tid; c < 128 * 8; c += 256) {
      int r = c >> 3, kc = c & 7;
      int gr = row0 + r;
      uint4 v = make_uint4(0, 0, 0, 0);
      if (gr < M) v = *(const uint4*)(A + (size_t)gr * 128 + k0 + kc * 8);
      *(uint4*)(As + r * 72 + kc * 8) = v;
    }
    for (int c = tid; c < BN * 8; c += 256) {
      int r = c >> 3, kc = c & 7;
      uint4 v = make_uint4(0, 0, 0, 0);
      if (r < WROWS) v = *(const uint4*)(Wb + (size_t)r * 128 + k0 + kc * 8);
      *(uint4*)(Ws + r * 72 + kc * 8) = v;
    }
    __syncthreads();
#pragma unroll
    for (int ks = 0; ks < 64; ks += 32) {
      bf16x8 af[4], bw[NT];
#pragma unroll
      for (int mt = 0; mt < 4; ++mt)
        af[mt] = *(const bf16x8*)(As + (wm * 64 + mt * 16 + lrow) * 72 + ks + quad * 8);
#pragma unroll
      for (int nt = 0; nt < NT; ++nt)
        bw[nt] = *(const bf16x8*)(Ws + (wn * NT * 16 + nt * 16 + lrow) * 72 + ks + quad * 8);
#pragma unroll
      for (int mt = 0; mt < 4; ++mt)
#pragma unroll
        for (int nt = 0; nt < NT; ++nt)
          acc[mt][nt] = __builtin_amdgcn_mfma_f32_16x16x32_bf16(
              af[mt], bw[nt], acc[mt][nt], 0, 0, 0);
    }
    __syncthreads();
  }
  // epilogue: C/D layout col=lane&15, row=quad*4+reg; branch-interleaved out
#pragma unroll
  for (int mt = 0; mt < 4; ++mt) {
#pragma unroll
    for (int nt = 0; nt < NT; ++nt) {
#pragma unroll
      for (int rg = 0; rg < 4; ++rg) {
        int row = row0 + wm * 64 + mt * 16 + quad * 4 + rg;
        if (row >= M) continue;
        int col = wn * NT * 16 + nt * 16 + lrow;
        int nd = (row < N0) ? row : row - N0;
        int hf = (row < N0) ? 0 : 1;
        float v = acc[mt][nt][rg];
        if (!L2) {
          size_t idx = (size_t)nd * 256 + hf * 128 + col;
          if (blockIdx.y == 0)
            Pb[idx] = f2b(v);
          else
            Rf[idx] = v;
        } else {
          if (col < 47)
            Pb[(size_t)nd * 128 + hf * 64 + col] = f2b(v);
          else if (col < 94)
            Rf[(size_t)nd * 128 + hf * 64 + (col - 47)] = v;
        }
      }
    }
  }
}

// ------------------------------ aggregation --------------------------------
// 1 wave per NODE, both branches. lane: half=lane>>5 -> branch, 4 cols/lane.
// One 512B gather request per edge (uint2/lane), unrolled x4.
template <bool WF32>
__global__ __launch_bounds__(256) void agg_dual128(
    const ushort* __restrict__ P2, const float* __restrict__ R2,
    const float* __restrict__ bias, const int* __restrict__ off,
    const int* __restrict__ csr, float* __restrict__ f0,
    float* __restrict__ f1, ushort* __restrict__ bout, int N) {
  int node = (blockIdx.x * blockDim.x + threadIdx.x) >> 6;
  int lane = threadIdx.x & 63;
  if (node >= N) return;
  int half = lane >> 5, lq = lane & 31;
  int b = off[node], e = off[node + 1];
  float a0 = 0.f, a1 = 0.f, a2 = 0.f, a3 = 0.f;
  int j = b;
  for (; j + 4 <= e; j += 4) {
    int s0 = csr[j], s1 = csr[j + 1], s2 = csr[j + 2], s3 = csr[j + 3];
    uint2 u0 = *(const uint2*)(P2 + (size_t)s0 * 256 + 4 * lane);
    uint2 u1 = *(const uint2*)(P2 + (size_t)s1 * 256 + 4 * lane);
    uint2 u2 = *(const uint2*)(P2 + (size_t)s2 * 256 + 4 * lane);
    uint2 u3 = *(const uint2*)(P2 + (size_t)s3 * 256 + 4 * lane);
    a0 += b2f_lo(u0.x) + b2f_lo(u1.x) + b2f_lo(u2.x) + b2f_lo(u3.x);
    a1 += b2f_hi(u0.x) + b2f_hi(u1.x) + b2f_hi(u2.x) + b2f_hi(u3.x);
    a2 += b2f_lo(u0.y) + b2f_lo(u1.y) + b2f_lo(u2.y) + b2f_lo(u3.y);
    a3 += b2f_hi(u0.y) + b2f_hi(u1.y) + b2f_hi(u2.y) + b2f_hi(u3.y);
  }
  for (; j < e; ++j) {
    uint2 u0 = *(const uint2*)(P2 + (size_t)csr[j] * 256 + 4 * lane);
    a0 += b2f_lo(u0.x);
    a1 += b2f_hi(u0.x);
    a2 += b2f_lo(u0.y);
    a3 += b2f_hi(u0.y);
  }
  float invd = 1.f / (float)max(e - b, 1);
  float4 rv = *(const float4*)(R2 + (size_t)node * 256 + 4 * lane);
  float4 bb = *(const float4*)(bias + 4 * lq);
  float o0 = fmaxf(a0 * invd + bb.x + rv.x, 0.f);
  float o1 = fmaxf(a1 * invd + bb.y + rv.y, 0.f);
  float o2 = fmaxf(a2 * invd + bb.z + rv.z, 0.f);
  float o3 = fmaxf(a3 * invd + bb.w + rv.w, 0.f);
  size_t arow = (size_t)(half ? N + node : node) * 128 + 4 * lq;
  ushort4 pk;
  pk.x = f2b(o0); pk.y = f2b(o1); pk.z = f2b(o2); pk.w = f2b(o3);
  *(ushort4*)(bout + arow) = pk;
  if (WF32) {
    float* dst = (half ? f1 : f0) + (size_t)node * 128 + 4 * lq;
    *(float4*)dst = make_float4(o0, o1, o2, o3);
  }
}

// layer 2: Pz/Rz [node][2][64]; 1 wave per node, 2 cols/lane; fused softmax.
__global__ __launch_bounds__(256) void agg47_dual(
    const ushort* __restrict__ Pz, const float* __restrict__ Rz,
    const float* __restrict__ bias, const int* __restrict__ off,
    const int* __restrict__ csr, float* __restrict__ z0,
    float* __restrict__ z1, float* __restrict__ y0, float* __restrict__ y1,
    int N) {
  int node = (blockIdx.x * blockDim.x + threadIdx.x) >> 6;
  int lane = threadIdx.x & 63;
  if (node >= N) return;
  int half = lane >> 5, lq = lane & 31;
  int c0 = 2 * lq, c1 = 2 * lq + 1;
  bool v0 = c0 < 47, v1 = c1 < 47;
  int b = off[node], e = off[node + 1];
  float a0 = 0.f, a1 = 0.f;
  int j = b;
  for (; j + 4 <= e; j += 4) {
    int s0 = csr[j], s1 = csr[j + 1], s2 = csr[j + 2], s3 = csr[j + 3];
    uint u0 = *(const uint*)(Pz + (size_t)s0 * 128 + 2 * lane);
    uint u1 = *(const uint*)(Pz + (size_t)s1 * 128 + 2 * lane);
    uint u2 = *(const uint*)(Pz + (size_t)s2 * 128 + 2 * lane);
    uint u3 = *(const uint*)(Pz + (size_t)s3 * 128 + 2 * lane);
    a0 += b2f_lo(u0) + b2f_lo(u1) + b2f_lo(u2) + b2f_lo(u3);
    a1 += b2f_hi(u0) + b2f_hi(u1) + b2f_hi(u2) + b2f_hi(u3);
  }
  for (; j < e; ++j) {
    uint u0 = *(const uint*)(Pz + (size_t)csr[j] * 128 + 2 * lane);
    a0 += b2f_lo(u0);
    a1 += b2f_hi(u0);
  }
  float invd = 1.f / (float)max(e - b, 1);
  float2 rv = *(const float2*)(Rz + (size_t)node * 128 + 2 * lane);
  float za = v0 ? (a0 * invd + bias[c0] + rv.x) : -INFINITY;
  float zb = v1 ? (a1 * invd + bias[c1] + rv.y) : -INFINITY;
  // half-wave (branch) reduction: xor masks <=16 stay within 32-lane half
  float m = fmaxf(za, zb);
#pragma unroll
  for (int d = 1; d < 32; d <<= 1) m = fmaxf(m, __shfl_xor(m, d, 64));
  float s = (v0 ? __expf(za - m) : 0.f) + (v1 ? __expf(zb - m) : 0.f);
#pragma unroll
  for (int d = 1; d < 32; d <<= 1) s += __shfl_xor(s, d, 64);
  float ls = logf(s) + m;
  float* zo = (half ? z1 : z0) + (size_t)node * 47;
  float* yo = (half ? y1 : y0) + (size_t)node * 47;
  if (v0) { zo[c0] = za; yo[c0] = za - ls; }
  if (v1) { zo[c1] = zb; yo[c1] = zb - ls; }
}

// ---------------------------------------------------------------------------
extern "C" void kernel_launch(void* const* d_in, const int* in_sizes, int n_in,
                              void* d_out, int out_size, void* d_ws,
                              size_t ws_size, hipStream_t stream) {
  const float* x = (const float*)d_in[0];
  const int* ei = (const int*)d_in[1];
  const float* noise = (const float*)d_in[2];
  const float* Wl0 = (const float*)d_in[3];
  const float* bl0 = (const float*)d_in[4];
  const float* Wr0 = (const float*)d_in[5];
  const float* Wl1 = (const float*)d_in[6];
  const float* bl1 = (const float*)d_in[7];
  const float* Wr1 = (const float*)d_in[8];
  const float* Wl2 = (const float*)d_in[9];
  const float* bl2 = (const float*)d_in[10];
  const float* Wr2 = (const float*)d_in[11];

  const int N = in_sizes[0] / 128;
  const int E = in_sizes[1] / 2;
  const int M = 2 * N;

  float* out = (float*)d_out;
  float* h_p = out;
  float* y_p = h_p + (size_t)N * 128;
  float* z_p = y_p + (size_t)N * 47;
  float* h_n = z_p + (size_t)N * 47;
  float* y_n = h_n + (size_t)N * 128;
  float* z_n = y_n + (size_t)N * 47;

  char* w = (char*)d_ws;
  auto alloc = [&](size_t bytes) {
    void* p = (void*)w;
    w += (bytes + 511) & ~(size_t)511;
    return p;
  };
  ushort* XB = (ushort*)alloc((size_t)M * 128 * 2);   // activations bf16 [M][128]
  ushort* Pb = (ushort*)alloc((size_t)M * 128 * 2);   // P2 / Pz interleaved
  float* Rf = (float*)alloc((size_t)M * 128 * 4);     // R2 / Rz interleaved
  ushort* WB0 = (ushort*)alloc(256 * 128 * 2);
  ushort* WB1 = (ushort*)alloc(256 * 128 * 2);
  ushort* WB2 = (ushort*)alloc(94 * 128 * 2);
  int* cnt = (int*)alloc((size_t)N * 4);
  int* off = (int*)alloc((size_t)(N + 1) * 4);
  int* cur = (int*)alloc((size_t)N * 4);
  int* loc = (int*)alloc((size_t)N * 4);
  int* bsum = (int*)alloc((size_t)256 * 4);
  int* csr = (int*)alloc((size_t)E * 4);

  conv_weights<<<(16384 + 255) / 256, 256, 0, stream>>>(
      Wl0, Wr0, Wl1, Wr1, Wl2, Wr2, WB0, WB1, WB2);

  // CSR build
  hipMemsetAsync(cnt, 0, (size_t)N * 4, stream);
  int eb = (E + 255) / 256;
  count_kernel<<<eb, 256, 0, stream>>>(ei + E, cnt, E);
  int sb = (N + 1023) / 1024;
  scan_blocks<<<sb, 256, 0, stream>>>(cnt, loc, bsum, N);
  scan_bsums<<<1, 256, 0, stream>>>(bsum, sb);
  scan_apply<<<(N + 255) / 256, 256, 0, stream>>>(loc, bsum, off, cur, N, E);
  fill_kernel<<<eb, 256, 0, stream>>>(ei, ei + E, cur, csr, E);

  int nwb = (N + 3) / 4;       // 1 wave/node
  int rb = (M + 127) / 128;    // GEMM row blocks

  noisy_convert<<<nwb, 256, 0, stream>>>(x, noise, XB, N);

  // layer 0
  gemm_bf16<4, false><<<dim3(rb, 2), 256, 0, stream>>>(XB, WB0, Pb, Rf, M);
  agg_dual128<false><<<nwb, 256, 0, stream>>>(Pb, Rf, bl0, off, csr, nullptr,
                                              nullptr, XB, N);
  // layer 1 (h outputs + bf16 for next layer)
  gemm_bf16<4, false><<<dim3(rb, 2), 256, 0, stream>>>(XB, WB1, Pb, Rf, M);
  agg_dual128<true><<<nwb, 256, 0, stream>>>(Pb, Rf, bl1, off, csr, h_p, h_n,
                                             XB, N);
  // layer 2 + fused log_softmax
  gemm_bf16<3, true><<<dim3(rb, 1), 256, 0, stream>>>(XB, WB2, Pb, Rf, M);
  agg47_dual<<<nwb, 256, 0, stream>>>(Pb, Rf, bl2, off, csr, z_p, z_n, y_p,
                                      y_n, N);
}